// Round 4
// baseline (553.463 us; speedup 1.0000x reference)
//
#include <hip/hip_runtime.h>
#include <hip/hip_bf16.h>
#include <stdint.h>

#define NN 50000
#define EE 800000
#define DD 64
#define RR 10
#define BB 4
#define NBKT 391            // buckets of 128 nodes: bucket = node >> 7

using u16 = unsigned short;
using u32 = unsigned int;

typedef short v8s __attribute__((ext_vector_type(8)));   // 8 bf16 (4 VGPRs)
typedef float v4f __attribute__((ext_vector_type(4)));   // MFMA accumulator

__device__ __forceinline__ u32 f2bf_rn(float x) {
    u32 u = __float_as_uint(x);
    return (u + 0x7FFFu + ((u >> 16) & 1u)) >> 16;
}
__device__ __forceinline__ u32 pack2bf(float a, float b) {
    return f2bf_rn(a) | (f2bf_rn(b) << 16);
}

// ---------------- feat fp32 -> bf16 ----------------
__global__ __launch_bounds__(256)
void k_cast(const float* __restrict__ feat, u16* __restrict__ featb) {
    int i = blockIdx.x * 256 + threadIdx.x;     // one uint4 (8 elems) each
    if (i >= NN * DD / 8) return;
    float4 f0 = reinterpret_cast<const float4*>(feat)[2 * i];
    float4 f1 = reinterpret_cast<const float4*>(feat)[2 * i + 1];
    uint4 o;
    o.x = pack2bf(f0.x, f0.y);
    o.y = pack2bf(f0.z, f0.w);
    o.z = pack2bf(f1.x, f1.y);
    o.w = pack2bf(f1.z, f1.w);
    reinterpret_cast<uint4*>(featb)[i] = o;
}

// ---------------- MFMA transform: 128 nodes x 64 outs per block ------------
__global__ __launch_bounds__(256, 2)
void k_transform_mfma(const u16* __restrict__ featb,
                      const float* __restrict__ weight,
                      const float* __restrict__ w_comp,
                      const float* __restrict__ self_w,
                      u16* __restrict__ xr, float* __restrict__ out) {
    __shared__ u16 sWt[64 * 72];
    __shared__ float sD[128 * 68];
    const int t = threadIdx.x;
    const int r = blockIdx.y;
    const int nbase = blockIdx.x * 128;

    if (r < RR) {
        const float c0 = w_comp[r * BB + 0];
        const float c1 = w_comp[r * BB + 1];
        const float c2 = w_comp[r * BB + 2];
        const float c3 = w_comp[r * BB + 3];
        #pragma unroll
        for (int qq = 0; qq < 16; ++qq) {
            int idx = t + 256 * qq;
            int n = idx & 63, k = idx >> 6;
            float v = c0 * weight[k * 64 + n] + c1 * weight[4096 + k * 64 + n] +
                      c2 * weight[8192 + k * 64 + n] + c3 * weight[12288 + k * 64 + n];
            sWt[n * 72 + k] = (u16)f2bf_rn(v);
        }
    } else {
        #pragma unroll
        for (int qq = 0; qq < 16; ++qq) {
            int idx = t + 256 * qq;
            int n = idx & 63, k = idx >> 6;
            sWt[n * 72 + k] = (u16)f2bf_rn(self_w[k * 64 + n]);
        }
    }
    __syncthreads();

    const int wv = t >> 6;
    const int L = t & 63;
    const int q = L >> 4;
    const int c = L & 15;

    v8s bf[4][2];
    #pragma unroll
    for (int nt = 0; nt < 4; ++nt)
        #pragma unroll
        for (int kh = 0; kh < 2; ++kh)
            bf[nt][kh] = *reinterpret_cast<const v8s*>(&sWt[(nt * 16 + c) * 72 + kh * 32 + q * 8]);

    v8s af[2][2];
    #pragma unroll
    for (int mt = 0; mt < 2; ++mt) {
        int g = nbase + wv * 32 + mt * 16 + c;
        const u16* p = featb + (size_t)((g < NN) ? g : 0) * DD;
        #pragma unroll
        for (int kh = 0; kh < 2; ++kh)
            af[mt][kh] = *reinterpret_cast<const v8s*>(p + kh * 32 + q * 8);
    }

    v4f acc[2][4];
    #pragma unroll
    for (int mt = 0; mt < 2; ++mt)
        #pragma unroll
        for (int nt = 0; nt < 4; ++nt) {
            acc[mt][nt] = (v4f)(0.f);
            #pragma unroll
            for (int kh = 0; kh < 2; ++kh)
                acc[mt][nt] = __builtin_amdgcn_mfma_f32_16x16x32_bf16(
                    af[mt][kh], bf[nt][kh], acc[mt][nt], 0, 0, 0);
        }

    #pragma unroll
    for (int mt = 0; mt < 2; ++mt) {
        int mrow = wv * 32 + mt * 16 + q * 4;
        #pragma unroll
        for (int nt = 0; nt < 4; ++nt)
            #pragma unroll
            for (int rg = 0; rg < 4; ++rg)
                sD[(mrow + rg) * 68 + nt * 16 + c] = acc[mt][nt][rg];
    }
    __syncthreads();

    const int row = t >> 1;
    const int cb = (t & 1) * 32;
    const int g = nbase + row;
    if (g < NN) {
        const float* sp = &sD[row * 68 + cb];
        if (r < RR) {
            u16* dp = xr + ((size_t)r * NN + g) * DD + cb;
            #pragma unroll
            for (int j = 0; j < 4; ++j) {
                float4 f0 = *reinterpret_cast<const float4*>(sp + j * 8);
                float4 f1 = *reinterpret_cast<const float4*>(sp + j * 8 + 4);
                uint4 o;
                o.x = pack2bf(f0.x, f0.y);
                o.y = pack2bf(f0.z, f0.w);
                o.z = pack2bf(f1.x, f1.y);
                o.w = pack2bf(f1.z, f1.w);
                *reinterpret_cast<uint4*>(dp + j * 8) = o;
            }
        } else {
            float* dp = out + (size_t)g * DD + cb;
            #pragma unroll
            for (int j = 0; j < 8; ++j)
                *reinterpret_cast<float4*>(dp + j * 4) =
                    *reinterpret_cast<const float4*>(sp + j * 4);
        }
    }
}

// ---------------- bucket histogram: 98 blocks x 8192 edges ----------------
__global__ __launch_bounds__(256)
void k_hist2(const int* __restrict__ dst, int* __restrict__ cnt) {
    __shared__ int lh[NBKT];
    const int t = threadIdx.x;
    for (int b = t; b < NBKT; b += 256) lh[b] = 0;
    __syncthreads();
    const int base_e = blockIdx.x * 8192;
    #pragma unroll
    for (int j = 0; j < 32; ++j) {
        int e = base_e + t + 256 * j;
        if (e < EE) atomicAdd(&lh[dst[e] >> 7], 1);
    }
    __syncthreads();
    for (int b = t; b < NBKT; b += 256) {
        int v = lh[b];
        if (v) atomicAdd(&cnt[b], v);
    }
}

// ---------------- exclusive scan of 391 bucket counts ----------------
__global__ __launch_bounds__(512)
void k_scan2(const int* __restrict__ cnt, int* __restrict__ base,
             int* __restrict__ cur) {
    __shared__ int s[512];
    int t = threadIdx.x;
    int v = (t < NBKT) ? cnt[t] : 0;
    s[t] = v;
    __syncthreads();
    #pragma unroll
    for (int off = 1; off < 512; off <<= 1) {
        int x = (t >= off) ? s[t - off] : 0;
        __syncthreads();
        s[t] += x;
        __syncthreads();
    }
    if (t < NBKT) {
        int b = s[t] - v;
        base[t] = b;
        cur[t] = b;
    }
}

// ---------------- binning: 49 blocks x 16384 edges, batched reservations ----
// rec word0 = src | (etype<<16) | (dst_local<<20); word1 = norm bits
__global__ __launch_bounds__(256)
void k_bin(const int* __restrict__ src, const int* __restrict__ dst,
           const int* __restrict__ etype, const float* __restrict__ norm,
           int* __restrict__ cur, uint2* __restrict__ rec) {
    __shared__ int lh[NBKT];
    __shared__ int gb[NBKT];
    __shared__ int lc[NBKT];
    const int t = threadIdx.x;
    const int cbase = blockIdx.x * 16384;
    for (int b = t; b < NBKT; b += 256) { lh[b] = 0; lc[b] = 0; }
    __syncthreads();
    #pragma unroll 4
    for (int j = 0; j < 64; ++j) {
        int e = cbase + t + 256 * j;
        if (e < EE) atomicAdd(&lh[dst[e] >> 7], 1);
    }
    __syncthreads();
    for (int b = t; b < NBKT; b += 256) {
        int c = lh[b];
        gb[b] = c ? atomicAdd(&cur[b], c) : 0;
    }
    __syncthreads();
    #pragma unroll 4
    for (int j = 0; j < 64; ++j) {
        int e = cbase + t + 256 * j;
        if (e < EE) {
            int d = dst[e];
            int b = d >> 7;
            int p = atomicAdd(&lc[b], 1);
            u32 w0 = (u32)src[e] | ((u32)etype[e] << 16) | ((u32)(d & 127) << 20);
            rec[gb[b] + p] = make_uint2(w0, __float_as_uint(norm[e]));
        }
    }
}

// ---------------- aggregate: one block per bucket, LDS fp32 accumulator ----
__global__ __launch_bounds__(512, 2)
void k_aggb(const int* __restrict__ base, const int* __restrict__ cnt,
            const uint2* __restrict__ rec, const u16* __restrict__ xr,
            float* __restrict__ out) {
    __shared__ float sAcc[128 * 64];    // 32 KB
    const int t = threadIdx.x;
    #pragma unroll
    for (int j = 0; j < 16; ++j) sAcc[t + 512 * j] = 0.f;
    __syncthreads();

    const int b = blockIdx.x;
    const int start = base[b];
    const int n_rec = cnt[b];
    const int lim = start + n_rec;
    const int hw = t >> 5;          // half-wave 0..15
    const int l = t & 31;           // lane within half-wave -> cols 2l, 2l+1

    const int iters = (n_rec + 31) >> 5;
    for (int it = 0; it < iters; ++it) {
        int i0 = start + it * 32 + hw * 2;
        int i1 = i0 + 1;
        uint2 r0 = (i0 < lim) ? rec[i0] : make_uint2(0u, 0u);
        uint2 r1 = (i1 < lim) ? rec[i1] : make_uint2(0u, 0u);
        float nm0 = (i0 < lim) ? __uint_as_float(r0.y) : 0.f;
        float nm1 = (i1 < lim) ? __uint_as_float(r1.y) : 0.f;
        size_t row0 = ((size_t)((r0.x >> 16) & 0xFu) * NN + (r0.x & 0xFFFFu)) * DD;
        size_t row1 = ((size_t)((r1.x >> 16) & 0xFu) * NN + (r1.x & 0xFFFFu)) * DD;
        u32 u0 = *reinterpret_cast<const u32*>(&xr[row0 + 2 * l]);
        u32 u1 = *reinterpret_cast<const u32*>(&xr[row1 + 2 * l]);
        int nl0 = (r0.x >> 20) & 0x7F;
        int nl1 = (r1.x >> 20) & 0x7F;
        atomicAdd(&sAcc[nl0 * 64 + 2 * l],     __uint_as_float((u0 & 0xFFFFu) << 16) * nm0);
        atomicAdd(&sAcc[nl0 * 64 + 2 * l + 1], __uint_as_float(u0 & 0xFFFF0000u) * nm0);
        atomicAdd(&sAcc[nl1 * 64 + 2 * l],     __uint_as_float((u1 & 0xFFFFu) << 16) * nm1);
        atomicAdd(&sAcc[nl1 * 64 + 2 * l + 1], __uint_as_float(u1 & 0xFFFF0000u) * nm1);
    }
    __syncthreads();

    // epilogue: out += acc, relu (out already holds self-loop term)
    const int nb0 = b * 128;
    float4* outv = reinterpret_cast<float4*>(out);
    #pragma unroll
    for (int j = 0; j < 4; ++j) {
        int idx4 = t + 512 * j;             // float4 index within tile (0..2047)
        int node = idx4 >> 4;
        if (nb0 + node < NN) {
            size_t g = (size_t)nb0 * 16 + idx4;
            float4 o = outv[g];
            const float4 a = *reinterpret_cast<const float4*>(&sAcc[idx4 * 4]);
            o.x = fmaxf(o.x + a.x, 0.f);
            o.y = fmaxf(o.y + a.y, 0.f);
            o.z = fmaxf(o.z + a.z, 0.f);
            o.w = fmaxf(o.w + a.w, 0.f);
            outv[g] = o;
        }
    }
}

// ---------------- fallbacks (R1/R2 paths, unchanged) ----------------
__global__ __launch_bounds__(256, 3)
void k_transform(const float* __restrict__ feat,
                 const float* __restrict__ weight,
                 const float* __restrict__ w_comp,
                 const float* __restrict__ self_w,
                 u16* __restrict__ xr,
                 float* __restrict__ out,
                 int rbase) {
    __shared__ float sW[DD * DD];
    __shared__ float sF[128 * 68];
    const int t = threadIdx.x;
    const int r = blockIdx.y + rbase;
    const int nbase = blockIdx.x * 128;

    if (r < RR) {
        const float c0 = w_comp[r * BB + 0];
        const float c1 = w_comp[r * BB + 1];
        const float c2 = w_comp[r * BB + 2];
        const float c3 = w_comp[r * BB + 3];
        #pragma unroll
        for (int qq = 0; qq < 16; ++qq) {
            int f = t + 256 * qq;
            sW[f] = c0 * weight[f] + c1 * weight[4096 + f] +
                    c2 * weight[8192 + f] + c3 * weight[12288 + f];
        }
    } else {
        #pragma unroll
        for (int qq = 0; qq < 16; ++qq) {
            int f = t + 256 * qq;
            sW[f] = self_w[f];
        }
    }

    #pragma unroll
    for (int qq = 0; qq < 8; ++qq) {
        int f4 = qq * 256 + t;
        int nl = f4 >> 4;
        int ic = (f4 & 15) << 2;
        int n = nbase + nl;
        float4 v = make_float4(0.f, 0.f, 0.f, 0.f);
        if (n < NN) v = reinterpret_cast<const float4*>(feat)[(size_t)n * 16 + (f4 & 15)];
        *reinterpret_cast<float4*>(&sF[nl * 68 + ic]) = v;
    }
    __syncthreads();

    const int to = t & 7;
    const int tn = t >> 3;

    float acc[4][8];
    #pragma unroll
    for (int j = 0; j < 4; ++j)
        #pragma unroll
        for (int m = 0; m < 8; ++m) acc[j][m] = 0.f;

    #pragma unroll 4
    for (int i0 = 0; i0 < DD; i0 += 4) {
        float wv[4][8];
        #pragma unroll
        for (int kq = 0; kq < 4; ++kq) {
            float4 a = *reinterpret_cast<const float4*>(&sW[(i0 + kq) * DD + to * 4]);
            float4 bq = *reinterpret_cast<const float4*>(&sW[(i0 + kq) * DD + 32 + to * 4]);
            wv[kq][0] = a.x; wv[kq][1] = a.y; wv[kq][2] = a.z; wv[kq][3] = a.w;
            wv[kq][4] = bq.x; wv[kq][5] = bq.y; wv[kq][6] = bq.z; wv[kq][7] = bq.w;
        }
        #pragma unroll
        for (int j = 0; j < 4; ++j) {
            float4 f = *reinterpret_cast<const float4*>(&sF[(tn + 32 * j) * 68 + i0]);
            float fv[4] = {f.x, f.y, f.z, f.w};
            #pragma unroll
            for (int kq = 0; kq < 4; ++kq)
                #pragma unroll
                for (int m = 0; m < 8; ++m)
                    acc[j][m] = fmaf(fv[kq], wv[kq][m], acc[j][m]);
        }
    }

    if (r < RR) {
        #pragma unroll
        for (int j = 0; j < 4; ++j) {
            int n = nbase + tn + 32 * j;
            if (n < NN) {
                size_t row = ((size_t)r * NN + n) * DD;
                u32 p0 = pack2bf(acc[j][0], acc[j][1]);
                u32 p1 = pack2bf(acc[j][2], acc[j][3]);
                u32 p2 = pack2bf(acc[j][4], acc[j][5]);
                u32 p3 = pack2bf(acc[j][6], acc[j][7]);
                *reinterpret_cast<uint2*>(&xr[row + to * 4]) = make_uint2(p0, p1);
                *reinterpret_cast<uint2*>(&xr[row + 32 + to * 4]) = make_uint2(p2, p3);
            }
        }
    } else {
        #pragma unroll
        for (int j = 0; j < 4; ++j) {
            int n = nbase + tn + 32 * j;
            if (n < NN) {
                size_t row = (size_t)n * DD;
                *reinterpret_cast<float4*>(&out[row + to * 4]) =
                    make_float4(acc[j][0], acc[j][1], acc[j][2], acc[j][3]);
                *reinterpret_cast<float4*>(&out[row + 32 + to * 4]) =
                    make_float4(acc[j][4], acc[j][5], acc[j][6], acc[j][7]);
            }
        }
    }
}

__global__ __launch_bounds__(256)
void k_edges(const int* __restrict__ src, const int* __restrict__ dst,
             const int* __restrict__ etype, const float* __restrict__ norm,
             const u16* __restrict__ xr, float* __restrict__ out) {
    int gtid = blockIdx.x * 256 + threadIdx.x;
    int e = gtid >> 4;
    int l = gtid & 15;
    if (e >= EE) return;
    int s = src[e];
    int d = dst[e];
    int rt = etype[e];
    float nm = norm[e];
    size_t row = ((size_t)rt * NN + s) * DD;
    uint2 u = *reinterpret_cast<const uint2*>(&xr[row + l * 4]);
    float f0 = __uint_as_float((u.x & 0xFFFFu) << 16);
    float f1 = __uint_as_float(u.x & 0xFFFF0000u);
    float f2 = __uint_as_float((u.y & 0xFFFFu) << 16);
    float f3 = __uint_as_float(u.y & 0xFFFF0000u);
    float* op = out + (size_t)d * DD + l * 4;
    atomicAdd(op + 0, f0 * nm);
    atomicAdd(op + 1, f1 * nm);
    atomicAdd(op + 2, f2 * nm);
    atomicAdd(op + 3, f3 * nm);
}

__global__ void k_makeW(const float* __restrict__ weight,
                        const float* __restrict__ w_comp,
                        float* __restrict__ W) {
    int f = blockIdx.x * 256 + threadIdx.x;
    if (f >= RR * 4096) return;
    int r = f >> 12;
    int io = f & 4095;
    float v = 0.f;
    #pragma unroll
    for (int b = 0; b < BB; ++b) v += w_comp[r * BB + b] * weight[b * 4096 + io];
    W[f] = v;
}

__global__ __launch_bounds__(256)
void k_edges_direct(const int* __restrict__ src, const int* __restrict__ dst,
                    const int* __restrict__ etype, const float* __restrict__ norm,
                    const float* __restrict__ feat, const float* __restrict__ W,
                    float* __restrict__ out) {
    int gtid = blockIdx.x * 256 + threadIdx.x;
    int e = gtid >> 6;
    int lane = gtid & 63;
    if (e >= EE) return;
    int s = src[e];
    int d = dst[e];
    int rt = etype[e];
    float nm = norm[e];
    const float* fr = feat + (size_t)s * DD;
    const float* Wr = W + (size_t)rt * 4096;
    float acc = 0.f;
    #pragma unroll
    for (int i = 0; i < DD; ++i) acc = fmaf(fr[i], Wr[i * DD + lane], acc);
    atomicAdd(&out[(size_t)d * DD + lane], acc * nm);
}

__global__ __launch_bounds__(256)
void k_relu(float* __restrict__ out) {
    int i = blockIdx.x * 256 + threadIdx.x;
    float4* p = reinterpret_cast<float4*>(out);
    float4 v = p[i];
    v.x = fmaxf(v.x, 0.f);
    v.y = fmaxf(v.y, 0.f);
    v.z = fmaxf(v.z, 0.f);
    v.w = fmaxf(v.w, 0.f);
    p[i] = v;
}

extern "C" void kernel_launch(void* const* d_in, const int* in_sizes, int n_in,
                              void* d_out, int out_size, void* d_ws, size_t ws_size,
                              hipStream_t stream) {
    const float* feat   = (const float*)d_in[0];
    const int*   src    = (const int*)d_in[1];
    const int*   dst    = (const int*)d_in[2];
    const int*   etype  = (const int*)d_in[3];
    const float* norm   = (const float*)d_in[4];
    const float* weight = (const float*)d_in[5];
    const float* w_comp = (const float*)d_in[6];
    const float* self_w = (const float*)d_in[7];
    float* out = (float*)d_out;

    // ws layout; rec region doubles as feat_bf16 (featb dead before k_bin)
    const size_t sz_xr    = (size_t)RR * NN * DD * sizeof(u16);   // 64,000,000
    const size_t off_cnt  = sz_xr;                                 // NBKT ints
    const size_t off_base = off_cnt + 1568;                        // NBKT ints
    const size_t off_cur  = off_base + 1568;                       // NBKT ints
    const size_t off_rec  = off_cur + 1568 + 8;                    // 16B-aligned
    const size_t need_full = off_rec + (size_t)EE * 8;             // ~70.4 MB

    dim3 blk(256);
    char* ws = (char*)d_ws;

    if (ws_size >= need_full) {
        u16*  xr    = (u16*)ws;
        int*  cnt   = (int*)(ws + off_cnt);
        int*  basep = (int*)(ws + off_base);
        int*  cur   = (int*)(ws + off_cur);
        uint2* rec  = (uint2*)(ws + off_rec);
        u16*  featb = (u16*)(ws + off_rec);    // overlay

        k_cast<<<dim3((NN * DD / 8 + 255) / 256), blk, 0, stream>>>(feat, featb);
        k_transform_mfma<<<dim3(391, RR + 1), blk, 0, stream>>>(featb, weight, w_comp,
                                                                self_w, xr, out);
        hipMemsetAsync(cnt, 0, 1568, stream);
        k_hist2<<<dim3(98), blk, 0, stream>>>(dst, cnt);
        k_scan2<<<dim3(1), dim3(512), 0, stream>>>(cnt, basep, cur);
        k_bin<<<dim3(49), blk, 0, stream>>>(src, dst, etype, norm, cur, rec);
        k_aggb<<<dim3(NBKT), dim3(512), 0, stream>>>(basep, cnt, rec, xr, out);
    } else if (ws_size >= sz_xr) {
        u16* xr = (u16*)d_ws;
        k_transform<<<dim3(391, RR + 1), blk, 0, stream>>>(feat, weight, w_comp,
                                                           self_w, xr, out, 0);
        k_edges<<<dim3(EE * 16 / 256), blk, 0, stream>>>(src, dst, etype, norm, xr, out);
        k_relu<<<dim3(NN * DD / 4 / 256), blk, 0, stream>>>(out);
    } else {
        k_transform<<<dim3(391, 1), blk, 0, stream>>>(feat, weight, w_comp,
                                                      self_w, (u16*)d_ws, out, RR);
        float* W = (float*)d_ws;
        k_makeW<<<dim3(160), blk, 0, stream>>>(weight, w_comp, W);
        k_edges_direct<<<dim3(EE * 64 / 256), blk, 0, stream>>>(src, dst, etype, norm,
                                                                feat, W, out);
        k_relu<<<dim3(NN * DD / 4 / 256), blk, 0, stream>>>(out);
    }
}

// Round 5
// 237.656 us; speedup vs baseline: 2.3288x; 2.3288x over previous
//
#include <hip/hip_runtime.h>
#include <hip/hip_bf16.h>
#include <stdint.h>

#define NN 50000
#define EE 800000
#define DD 64
#define RR 10
#define BB 4
#define NPAD 50176          // 196*256, padded node count for scan
#define NBLK 196
#define TBLK 4301           // 391 * 11 transform blocks in k_big
#define SBLK 3125           // scatter blocks in k_big

using u16 = unsigned short;
using u32 = unsigned int;

typedef short v8s __attribute__((ext_vector_type(8)));   // 8 bf16 (4 VGPRs)
typedef float v4f __attribute__((ext_vector_type(4)));   // MFMA accumulator

__device__ __forceinline__ u32 f2bf_rn(float x) {
    u32 u = __float_as_uint(x);
    return (u + 0x7FFFu + ((u >> 16) & 1u)) >> 16;
}
__device__ __forceinline__ u32 pack2bf(float a, float b) {
    return f2bf_rn(a) | (f2bf_rn(b) << 16);
}

// ============ mega-kernel: transform (blocks < tcount) + scatter ============
// Transform block tb (= blockIdx.x + tb_off): r = tb/391, nbase = (tb%391)*128.
// r < RR: write bf16 xr row; r == RR: self-loop -> fp32 out (overwrites poison).
// Scatter block: 256 edges, cursor-allocate into per-node CSR, write rec.
__global__ __launch_bounds__(256, 2)
void k_big(const float* __restrict__ feat,
           const float* __restrict__ weight,
           const float* __restrict__ w_comp,
           const float* __restrict__ self_w,
           const int* __restrict__ src, const int* __restrict__ dst,
           const int* __restrict__ etype, const float* __restrict__ norm,
           int* __restrict__ cur, uint2* __restrict__ rec,
           u16* __restrict__ xr, float* __restrict__ out,
           int tcount, int tb_off) {
    // LDS union: phase A = sWt (9216 B) + sFb (18432 B); phase B = sD (34816 B)
    __shared__ __align__(16) char smem[34816];
    u16*   sWt = (u16*)smem;                  // Wt[n][k], stride 72 u16 (144 B)
    u16*   sFb = (u16*)(smem + 9216);         // feat bf16 [128][72]
    float* sD  = (float*)smem;                // epilogue transpose [128][68]

    const int t = threadIdx.x;

    if ((int)blockIdx.x >= tcount) {
        // ---------------- scatter ----------------
        int e = ((int)blockIdx.x - tcount) * 256 + t;
        if (e < EE) {
            int d = dst[e];
            int pos = atomicAdd(&cur[d], 1);
            rec[pos] = make_uint2((u32)src[e] | ((u32)etype[e] << 16),
                                  __float_as_uint(norm[e]));
        }
        return;
    }

    // ---------------- transform ----------------
    const int tb = (int)blockIdx.x + tb_off;
    const int r = tb / 391;
    const int nbase = (tb % 391) * 128;

    // stage W_r^T into sWt (bf16): Wt[n][k] = W[k][n]
    if (r < RR) {
        const float c0 = w_comp[r * BB + 0];
        const float c1 = w_comp[r * BB + 1];
        const float c2 = w_comp[r * BB + 2];
        const float c3 = w_comp[r * BB + 3];
        #pragma unroll
        for (int qq = 0; qq < 16; ++qq) {
            int idx = t + 256 * qq;          // 0..4095
            int n = idx & 63, k = idx >> 6;
            float v = c0 * weight[k * 64 + n] + c1 * weight[4096 + k * 64 + n] +
                      c2 * weight[8192 + k * 64 + n] + c3 * weight[12288 + k * 64 + n];
            sWt[n * 72 + k] = (u16)f2bf_rn(v);
        }
    } else {
        #pragma unroll
        for (int qq = 0; qq < 16; ++qq) {
            int idx = t + 256 * qq;
            int n = idx & 63, k = idx >> 6;
            sWt[n * 72 + k] = (u16)f2bf_rn(self_w[k * 64 + n]);
        }
    }

    // stage feat tile fp32 -> bf16 into sFb (coalesced float4 global loads)
    #pragma unroll
    for (int qq = 0; qq < 8; ++qq) {
        int f4 = qq * 256 + t;               // 0..2047
        int nl = f4 >> 4;                    // row 0..127
        int ic = (f4 & 15) << 2;             // col 0,4,..,60
        int n = nbase + nl;
        float4 v = make_float4(0.f, 0.f, 0.f, 0.f);
        if (n < NN) v = reinterpret_cast<const float4*>(feat)[(size_t)n * 16 + (f4 & 15)];
        *reinterpret_cast<uint2*>(&sFb[nl * 72 + ic]) =
            make_uint2(pack2bf(v.x, v.y), pack2bf(v.z, v.w));
    }
    __syncthreads();

    const int wv = t >> 6;
    const int L = t & 63;
    const int q = L >> 4;
    const int c = L & 15;

    v8s bf[4][2];
    #pragma unroll
    for (int nt = 0; nt < 4; ++nt)
        #pragma unroll
        for (int kh = 0; kh < 2; ++kh)
            bf[nt][kh] = *reinterpret_cast<const v8s*>(&sWt[(nt * 16 + c) * 72 + kh * 32 + q * 8]);

    v8s af[2][2];
    #pragma unroll
    for (int mt = 0; mt < 2; ++mt) {
        int row = wv * 32 + mt * 16 + c;
        #pragma unroll
        for (int kh = 0; kh < 2; ++kh)
            af[mt][kh] = *reinterpret_cast<const v8s*>(&sFb[row * 72 + kh * 32 + q * 8]);
    }
    __syncthreads();   // all frag reads done before sD overwrites sWt/sFb

    v4f acc[2][4];
    #pragma unroll
    for (int mt = 0; mt < 2; ++mt)
        #pragma unroll
        for (int nt = 0; nt < 4; ++nt) {
            acc[mt][nt] = (v4f)(0.f);
            #pragma unroll
            for (int kh = 0; kh < 2; ++kh)
                acc[mt][nt] = __builtin_amdgcn_mfma_f32_16x16x32_bf16(
                    af[mt][kh], bf[nt][kh], acc[mt][nt], 0, 0, 0);
        }

    // C/D layout: D[m=q*4+reg][n=c]
    #pragma unroll
    for (int mt = 0; mt < 2; ++mt) {
        int mrow = wv * 32 + mt * 16 + q * 4;
        #pragma unroll
        for (int nt = 0; nt < 4; ++nt)
            #pragma unroll
            for (int rg = 0; rg < 4; ++rg)
                sD[(mrow + rg) * 68 + nt * 16 + c] = acc[mt][nt][rg];
    }
    __syncthreads();

    const int row = t >> 1;
    const int cb = (t & 1) * 32;
    const int g = nbase + row;
    if (g < NN) {
        const float* sp = &sD[row * 68 + cb];
        if (r < RR) {
            u16* dp = xr + ((size_t)r * NN + g) * DD + cb;
            #pragma unroll
            for (int j = 0; j < 4; ++j) {
                float4 f0 = *reinterpret_cast<const float4*>(sp + j * 8);
                float4 f1 = *reinterpret_cast<const float4*>(sp + j * 8 + 4);
                uint4 o;
                o.x = pack2bf(f0.x, f0.y);
                o.y = pack2bf(f0.z, f0.w);
                o.z = pack2bf(f1.x, f1.y);
                o.w = pack2bf(f1.z, f1.w);
                *reinterpret_cast<uint4*>(dp + j * 8) = o;
            }
        } else {
            float* dp = out + (size_t)g * DD + cb;
            #pragma unroll
            for (int j = 0; j < 8; ++j)
                *reinterpret_cast<float4*>(dp + j * 4) =
                    *reinterpret_cast<const float4*>(sp + j * 4);
        }
    }
}

// ---------------- per-node histogram ----------------
__global__ __launch_bounds__(256)
void k_hist(const int* __restrict__ dst, int* __restrict__ count) {
    int e = blockIdx.x * 256 + threadIdx.x;
    if (e < EE) atomicAdd(&count[dst[e]], 1);
}

__global__ __launch_bounds__(256)
void k_blocksum(const int* __restrict__ count, int* __restrict__ bsum) {
    __shared__ int s[256];
    int t = threadIdx.x;
    s[t] = count[blockIdx.x * 256 + t];
    __syncthreads();
    #pragma unroll
    for (int off = 128; off > 0; off >>= 1) {
        if (t < off) s[t] += s[t + off];
        __syncthreads();
    }
    if (t == 0) bsum[blockIdx.x] = s[0];
}

// Fused: each block scans the 196 block-sums itself, then its local 256 counts.
__global__ __launch_bounds__(256)
void k_offsets2(const int* __restrict__ count, const int* __restrict__ bsum,
                int* __restrict__ base, int* __restrict__ cursor) {
    __shared__ int sb[256];
    __shared__ int s[256];
    int t = threadIdx.x;
    int bv = (t < NBLK) ? bsum[t] : 0;
    sb[t] = bv;
    __syncthreads();
    #pragma unroll
    for (int off = 1; off < 256; off <<= 1) {
        int x = (t >= off) ? sb[t - off] : 0;
        __syncthreads();
        sb[t] += x;
        __syncthreads();
    }
    // exclusive prefix for this block
    int bprefix = sb[blockIdx.x] - bsum[blockIdx.x];

    int i = blockIdx.x * 256 + t;
    int v = count[i];
    s[t] = v;
    __syncthreads();
    #pragma unroll
    for (int off = 1; off < 256; off <<= 1) {
        int x = (t >= off) ? s[t - off] : 0;
        __syncthreads();
        s[t] += x;
        __syncthreads();
    }
    int b = s[t] - v + bprefix;
    base[i] = b;
    cursor[i] = b;
}

// --------- aggregate: one wave per dst node, 8 records in flight/wave -------
__global__ __launch_bounds__(256)
void k_agg(const int* __restrict__ base, const int* __restrict__ cnt,
           const uint2* __restrict__ rec, const u16* __restrict__ xr,
           float* __restrict__ out) {
    int n = (blockIdx.x * 256 + threadIdx.x) >> 6;
    int L = threadIdx.x & 63;
    if (n >= NN) return;
    const int h = L >> 5;        // which record of each pair
    const int c = L & 31;        // col pair: cols 2c, 2c+1
    int st = base[n];
    int cn = cnt[n];
    float a0 = 0.f, a1 = 0.f;
    int k = 0;
    for (; k + 8 <= cn; k += 8) {
        uint2 r0 = rec[st + k + h];
        uint2 r1 = rec[st + k + 2 + h];
        uint2 r2 = rec[st + k + 4 + h];
        uint2 r3 = rec[st + k + 6 + h];
        size_t w0 = ((size_t)(r0.x >> 16) * NN + (r0.x & 0xFFFFu)) * DD;
        size_t w1 = ((size_t)(r1.x >> 16) * NN + (r1.x & 0xFFFFu)) * DD;
        size_t w2 = ((size_t)(r2.x >> 16) * NN + (r2.x & 0xFFFFu)) * DD;
        size_t w3 = ((size_t)(r3.x >> 16) * NN + (r3.x & 0xFFFFu)) * DD;
        u32 u0 = *reinterpret_cast<const u32*>(&xr[w0 + 2 * c]);
        u32 u1 = *reinterpret_cast<const u32*>(&xr[w1 + 2 * c]);
        u32 u2 = *reinterpret_cast<const u32*>(&xr[w2 + 2 * c]);
        u32 u3 = *reinterpret_cast<const u32*>(&xr[w3 + 2 * c]);
        float n0 = __uint_as_float(r0.y), n1 = __uint_as_float(r1.y);
        float n2 = __uint_as_float(r2.y), n3 = __uint_as_float(r3.y);
        a0 = fmaf(__uint_as_float((u0 & 0xFFFFu) << 16), n0, a0);
        a1 = fmaf(__uint_as_float(u0 & 0xFFFF0000u), n0, a1);
        a0 = fmaf(__uint_as_float((u1 & 0xFFFFu) << 16), n1, a0);
        a1 = fmaf(__uint_as_float(u1 & 0xFFFF0000u), n1, a1);
        a0 = fmaf(__uint_as_float((u2 & 0xFFFFu) << 16), n2, a0);
        a1 = fmaf(__uint_as_float(u2 & 0xFFFF0000u), n2, a1);
        a0 = fmaf(__uint_as_float((u3 & 0xFFFFu) << 16), n3, a0);
        a1 = fmaf(__uint_as_float(u3 & 0xFFFF0000u), n3, a1);
    }
    for (; k + 4 <= cn; k += 4) {
        uint2 r0 = rec[st + k + h];
        uint2 r1 = rec[st + k + 2 + h];
        size_t w0 = ((size_t)(r0.x >> 16) * NN + (r0.x & 0xFFFFu)) * DD;
        size_t w1 = ((size_t)(r1.x >> 16) * NN + (r1.x & 0xFFFFu)) * DD;
        u32 u0 = *reinterpret_cast<const u32*>(&xr[w0 + 2 * c]);
        u32 u1 = *reinterpret_cast<const u32*>(&xr[w1 + 2 * c]);
        float n0 = __uint_as_float(r0.y), n1 = __uint_as_float(r1.y);
        a0 = fmaf(__uint_as_float((u0 & 0xFFFFu) << 16), n0, a0);
        a1 = fmaf(__uint_as_float(u0 & 0xFFFF0000u), n0, a1);
        a0 = fmaf(__uint_as_float((u1 & 0xFFFFu) << 16), n1, a0);
        a1 = fmaf(__uint_as_float(u1 & 0xFFFF0000u), n1, a1);
    }
    for (int kk = k + h; kk < cn; kk += 2) {
        uint2 r0 = rec[st + kk];
        size_t w0 = ((size_t)(r0.x >> 16) * NN + (r0.x & 0xFFFFu)) * DD;
        u32 u0 = *reinterpret_cast<const u32*>(&xr[w0 + 2 * c]);
        float n0 = __uint_as_float(r0.y);
        a0 = fmaf(__uint_as_float((u0 & 0xFFFFu) << 16), n0, a0);
        a1 = fmaf(__uint_as_float(u0 & 0xFFFF0000u), n0, a1);
    }
    a0 += __shfl_xor(a0, 32);
    a1 += __shfl_xor(a1, 32);
    if (h == 0) {
        size_t o = (size_t)n * DD + 2 * c;
        float2 v = *reinterpret_cast<const float2*>(&out[o]);
        v.x = fmaxf(v.x + a0, 0.f);
        v.y = fmaxf(v.y + a1, 0.f);
        *reinterpret_cast<float2*>(&out[o]) = v;
    }
}

// ---------------- fallbacks ----------------
__global__ __launch_bounds__(256)
void k_edges(const int* __restrict__ src, const int* __restrict__ dst,
             const int* __restrict__ etype, const float* __restrict__ norm,
             const u16* __restrict__ xr, float* __restrict__ out) {
    int gtid = blockIdx.x * 256 + threadIdx.x;
    int e = gtid >> 4;
    int l = gtid & 15;
    if (e >= EE) return;
    int s = src[e];
    int d = dst[e];
    int rt = etype[e];
    float nm = norm[e];
    size_t row = ((size_t)rt * NN + s) * DD;
    uint2 u = *reinterpret_cast<const uint2*>(&xr[row + l * 4]);
    float f0 = __uint_as_float((u.x & 0xFFFFu) << 16);
    float f1 = __uint_as_float(u.x & 0xFFFF0000u);
    float f2 = __uint_as_float((u.y & 0xFFFFu) << 16);
    float f3 = __uint_as_float(u.y & 0xFFFF0000u);
    float* op = out + (size_t)d * DD + l * 4;
    atomicAdd(op + 0, f0 * nm);
    atomicAdd(op + 1, f1 * nm);
    atomicAdd(op + 2, f2 * nm);
    atomicAdd(op + 3, f3 * nm);
}

__global__ void k_makeW(const float* __restrict__ weight,
                        const float* __restrict__ w_comp,
                        float* __restrict__ W) {
    int f = blockIdx.x * 256 + threadIdx.x;
    if (f >= RR * 4096) return;
    int r = f >> 12;
    int io = f & 4095;
    float v = 0.f;
    #pragma unroll
    for (int b = 0; b < BB; ++b) v += w_comp[r * BB + b] * weight[b * 4096 + io];
    W[f] = v;
}

__global__ __launch_bounds__(256)
void k_edges_direct(const int* __restrict__ src, const int* __restrict__ dst,
                    const int* __restrict__ etype, const float* __restrict__ norm,
                    const float* __restrict__ feat, const float* __restrict__ W,
                    float* __restrict__ out) {
    int gtid = blockIdx.x * 256 + threadIdx.x;
    int e = gtid >> 6;
    int lane = gtid & 63;
    if (e >= EE) return;
    int s = src[e];
    int d = dst[e];
    int rt = etype[e];
    float nm = norm[e];
    const float* fr = feat + (size_t)s * DD;
    const float* Wr = W + (size_t)rt * 4096;
    float acc = 0.f;
    #pragma unroll
    for (int i = 0; i < DD; ++i) acc = fmaf(fr[i], Wr[i * DD + lane], acc);
    atomicAdd(&out[(size_t)d * DD + lane], acc * nm);
}

__global__ __launch_bounds__(256)
void k_relu(float* __restrict__ out) {
    int i = blockIdx.x * 256 + threadIdx.x;
    float4* p = reinterpret_cast<float4*>(out);
    float4 v = p[i];
    v.x = fmaxf(v.x, 0.f);
    v.y = fmaxf(v.y, 0.f);
    v.z = fmaxf(v.z, 0.f);
    v.w = fmaxf(v.w, 0.f);
    p[i] = v;
}

extern "C" void kernel_launch(void* const* d_in, const int* in_sizes, int n_in,
                              void* d_out, int out_size, void* d_ws, size_t ws_size,
                              hipStream_t stream) {
    const float* feat   = (const float*)d_in[0];
    const int*   src    = (const int*)d_in[1];
    const int*   dst    = (const int*)d_in[2];
    const int*   etype  = (const int*)d_in[3];
    const float* norm   = (const float*)d_in[4];
    const float* weight = (const float*)d_in[5];
    const float* w_comp = (const float*)d_in[6];
    const float* self_w = (const float*)d_in[7];
    float* out = (float*)d_out;

    const size_t sz_xr    = (size_t)RR * NN * DD * sizeof(u16);   // 64,000,000
    const size_t off_cnt  = sz_xr;                                 // NPAD ints
    const size_t off_bsum = off_cnt + (size_t)NPAD * 4;            // 256 ints
    const size_t off_base = off_bsum + 1024;                       // NPAD ints
    const size_t off_cur  = off_base + (size_t)NPAD * 4;           // NPAD ints
    const size_t off_rec  = off_cur + (size_t)NPAD * 4;            // EE uint2
    const size_t need_full = off_rec + (size_t)EE * 8;             // ~71.0 MB

    dim3 blk(256);
    char* ws = (char*)d_ws;

    if (ws_size >= need_full) {
        u16*  xr     = (u16*)ws;
        int*  cnt    = (int*)(ws + off_cnt);
        int*  bsum   = (int*)(ws + off_bsum);
        int*  basep  = (int*)(ws + off_base);
        int*  cursor = (int*)(ws + off_cur);
        uint2* rec   = (uint2*)(ws + off_rec);

        hipMemsetAsync(cnt, 0, (size_t)NPAD * 4, stream);
        k_hist<<<dim3((EE + 255) / 256), blk, 0, stream>>>(dst, cnt);
        k_blocksum<<<dim3(NBLK), blk, 0, stream>>>(cnt, bsum);
        k_offsets2<<<dim3(NBLK), blk, 0, stream>>>(cnt, bsum, basep, cursor);
        k_big<<<dim3(TBLK + SBLK), blk, 0, stream>>>(feat, weight, w_comp, self_w,
                                                     src, dst, etype, norm,
                                                     cursor, rec, xr, out, TBLK, 0);
        k_agg<<<dim3((NN * 64 + 255) / 256), blk, 0, stream>>>(basep, cnt, rec, xr, out);
    } else if (ws_size >= sz_xr) {
        u16* xr = (u16*)d_ws;
        // transform-only k_big (no scatter blocks; cur/rec unused)
        k_big<<<dim3(TBLK), blk, 0, stream>>>(feat, weight, w_comp, self_w,
                                              src, dst, etype, norm,
                                              (int*)d_ws, (uint2*)d_ws, xr, out,
                                              TBLK, 0);
        k_edges<<<dim3(EE * 16 / 256), blk, 0, stream>>>(src, dst, etype, norm, xr, out);
        k_relu<<<dim3(NN * DD / 4 / 256), blk, 0, stream>>>(out);
    } else {
        // self-loop only via k_big blocks 3910..4300 (r==10), then direct edges
        k_big<<<dim3(391), blk, 0, stream>>>(feat, weight, w_comp, self_w,
                                             src, dst, etype, norm,
                                             (int*)d_ws, (uint2*)d_ws, (u16*)d_ws, out,
                                             391, 3910);
        float* W = (float*)d_ws;
        k_makeW<<<dim3(160), blk, 0, stream>>>(weight, w_comp, W);
        k_edges_direct<<<dim3(EE * 64 / 256), blk, 0, stream>>>(src, dst, etype, norm,
                                                                feat, W, out);
        k_relu<<<dim3(NN * DD / 4 / 256), blk, 0, stream>>>(out);
    }
}

// Round 6
// 221.485 us; speedup vs baseline: 2.4989x; 1.0730x over previous
//
#include <hip/hip_runtime.h>
#include <hip/hip_bf16.h>
#include <stdint.h>

#define NN 50000
#define EE 800000
#define DD 64
#define RR 10
#define BB 4
#define NPAD 50176          // 196*256, padded node count for scan
#define NBLK 196
#define TBLK 4301           // 391 * 11 transform blocks in k_big
#define BBLK 196            // bin blocks in k_big (4096 edges each)
#define SORT_CAP 7168       // max records per bucket for in-LDS sort

using u16 = unsigned short;
using u32 = unsigned int;

typedef short v8s __attribute__((ext_vector_type(8)));   // 8 bf16 (4 VGPRs)
typedef float v4f __attribute__((ext_vector_type(4)));   // MFMA accumulator

__device__ __forceinline__ u32 f2bf_rn(float x) {
    u32 u = __float_as_uint(x);
    return (u + 0x7FFFu + ((u >> 16) & 1u)) >> 16;
}
__device__ __forceinline__ u32 pack2bf(float a, float b) {
    return f2bf_rn(a) | (f2bf_rn(b) << 16);
}

// ============ mega-kernel: transform blocks + bucket-bin blocks ============
// rec word0 = src(16b) | etype(4b, bits16-19) | dst_local(7b, bits20-26)
__global__ __launch_bounds__(256, 2)
void k_big(const float* __restrict__ feat,
           const float* __restrict__ weight,
           const float* __restrict__ w_comp,
           const float* __restrict__ self_w,
           const int* __restrict__ src, const int* __restrict__ dst,
           const int* __restrict__ etype, const float* __restrict__ norm,
           int* __restrict__ bcur, uint2* __restrict__ rec,
           u16* __restrict__ xr, float* __restrict__ out,
           int tcount, int tb_off) {
    // LDS union: transform phase A = sWt(9216)+sFb(18432); phase B = sD(34816)
    // bin: lh/gb/lcc ints (3*392*4 = 4704)
    __shared__ __align__(16) char smem[34816];
    const int t = threadIdx.x;

    if ((int)blockIdx.x >= tcount) {
        // ---------------- bucket binning, batched reservations ----------------
        int* lh  = (int*)smem;          // per-bucket count (this block)
        int* gb  = lh + 392;            // reserved global start
        int* lcc = gb + 392;            // running offset during scatter
        const int ebase = ((int)blockIdx.x - tcount) * 4096;
        for (int b = t; b < 392; b += 256) { lh[b] = 0; lcc[b] = 0; }
        __syncthreads();
        #pragma unroll 4
        for (int j = 0; j < 16; ++j) {
            int e = ebase + t + 256 * j;
            if (e < EE) atomicAdd(&lh[dst[e] >> 7], 1);
        }
        __syncthreads();
        for (int b = t; b < 392; b += 256) {
            int c = lh[b];
            gb[b] = c ? atomicAdd(&bcur[b], c) : 0;
        }
        __syncthreads();
        #pragma unroll 4
        for (int j = 0; j < 16; ++j) {
            int e = ebase + t + 256 * j;
            if (e < EE) {
                int d = dst[e];
                int b = d >> 7;
                int p = atomicAdd(&lcc[b], 1);
                u32 w0 = (u32)src[e] | ((u32)etype[e] << 16) | ((u32)(d & 127) << 20);
                rec[gb[b] + p] = make_uint2(w0, __float_as_uint(norm[e]));
            }
        }
        return;
    }

    // ---------------- transform ----------------
    u16*   sWt = (u16*)smem;                  // Wt[n][k], stride 72 u16
    u16*   sFb = (u16*)(smem + 9216);         // feat bf16 [128][72]
    float* sD  = (float*)smem;                // epilogue transpose [128][68]

    const int tb = (int)blockIdx.x + tb_off;
    const int r = tb / 391;
    const int nbase = (tb % 391) * 128;

    if (r < RR) {
        const float c0 = w_comp[r * BB + 0];
        const float c1 = w_comp[r * BB + 1];
        const float c2 = w_comp[r * BB + 2];
        const float c3 = w_comp[r * BB + 3];
        #pragma unroll
        for (int qq = 0; qq < 16; ++qq) {
            int idx = t + 256 * qq;
            int n = idx & 63, k = idx >> 6;
            float v = c0 * weight[k * 64 + n] + c1 * weight[4096 + k * 64 + n] +
                      c2 * weight[8192 + k * 64 + n] + c3 * weight[12288 + k * 64 + n];
            sWt[n * 72 + k] = (u16)f2bf_rn(v);
        }
    } else {
        #pragma unroll
        for (int qq = 0; qq < 16; ++qq) {
            int idx = t + 256 * qq;
            int n = idx & 63, k = idx >> 6;
            sWt[n * 72 + k] = (u16)f2bf_rn(self_w[k * 64 + n]);
        }
    }

    #pragma unroll
    for (int qq = 0; qq < 8; ++qq) {
        int f4 = qq * 256 + t;
        int nl = f4 >> 4;
        int ic = (f4 & 15) << 2;
        int n = nbase + nl;
        float4 v = make_float4(0.f, 0.f, 0.f, 0.f);
        if (n < NN) v = reinterpret_cast<const float4*>(feat)[(size_t)n * 16 + (f4 & 15)];
        *reinterpret_cast<uint2*>(&sFb[nl * 72 + ic]) =
            make_uint2(pack2bf(v.x, v.y), pack2bf(v.z, v.w));
    }
    __syncthreads();

    const int wv = t >> 6;
    const int L = t & 63;
    const int q = L >> 4;
    const int c = L & 15;

    v8s bf[4][2];
    #pragma unroll
    for (int nt = 0; nt < 4; ++nt)
        #pragma unroll
        for (int kh = 0; kh < 2; ++kh)
            bf[nt][kh] = *reinterpret_cast<const v8s*>(&sWt[(nt * 16 + c) * 72 + kh * 32 + q * 8]);

    v8s af[2][2];
    #pragma unroll
    for (int mt = 0; mt < 2; ++mt) {
        int row = wv * 32 + mt * 16 + c;
        #pragma unroll
        for (int kh = 0; kh < 2; ++kh)
            af[mt][kh] = *reinterpret_cast<const v8s*>(&sFb[row * 72 + kh * 32 + q * 8]);
    }
    __syncthreads();

    v4f acc[2][4];
    #pragma unroll
    for (int mt = 0; mt < 2; ++mt)
        #pragma unroll
        for (int nt = 0; nt < 4; ++nt) {
            acc[mt][nt] = (v4f)(0.f);
            #pragma unroll
            for (int kh = 0; kh < 2; ++kh)
                acc[mt][nt] = __builtin_amdgcn_mfma_f32_16x16x32_bf16(
                    af[mt][kh], bf[nt][kh], acc[mt][nt], 0, 0, 0);
        }

    #pragma unroll
    for (int mt = 0; mt < 2; ++mt) {
        int mrow = wv * 32 + mt * 16 + q * 4;
        #pragma unroll
        for (int nt = 0; nt < 4; ++nt)
            #pragma unroll
            for (int rg = 0; rg < 4; ++rg)
                sD[(mrow + rg) * 68 + nt * 16 + c] = acc[mt][nt][rg];
    }
    __syncthreads();

    const int row = t >> 1;
    const int cb = (t & 1) * 32;
    const int g = nbase + row;
    if (g < NN) {
        const float* sp = &sD[row * 68 + cb];
        if (r < RR) {
            u16* dp = xr + ((size_t)r * NN + g) * DD + cb;
            #pragma unroll
            for (int j = 0; j < 4; ++j) {
                float4 f0 = *reinterpret_cast<const float4*>(sp + j * 8);
                float4 f1 = *reinterpret_cast<const float4*>(sp + j * 8 + 4);
                uint4 o;
                o.x = pack2bf(f0.x, f0.y);
                o.y = pack2bf(f0.z, f0.w);
                o.z = pack2bf(f1.x, f1.y);
                o.w = pack2bf(f1.z, f1.w);
                *reinterpret_cast<uint4*>(dp + j * 8) = o;
            }
        } else {
            float* dp = out + (size_t)g * DD + cb;
            #pragma unroll
            for (int j = 0; j < 8; ++j)
                *reinterpret_cast<float4*>(dp + j * 4) =
                    *reinterpret_cast<const float4*>(sp + j * 4);
        }
    }
}

// ---------------- per-node histogram ----------------
__global__ __launch_bounds__(256)
void k_hist(const int* __restrict__ dst, int* __restrict__ count) {
    int e = blockIdx.x * 256 + threadIdx.x;
    if (e < EE) atomicAdd(&count[dst[e]], 1);
}

__global__ __launch_bounds__(256)
void k_blocksum(const int* __restrict__ count, int* __restrict__ bsum) {
    __shared__ int s[256];
    int t = threadIdx.x;
    s[t] = count[blockIdx.x * 256 + t];
    __syncthreads();
    #pragma unroll
    for (int off = 128; off > 0; off >>= 1) {
        if (t < off) s[t] += s[t + off];
        __syncthreads();
    }
    if (t == 0) bsum[blockIdx.x] = s[0];
}

// Fused scan: per-node base; also per-bucket cursor init (bucket = node>>7).
__global__ __launch_bounds__(256)
void k_offsets2(const int* __restrict__ count, const int* __restrict__ bsum,
                int* __restrict__ base, int* __restrict__ bcur) {
    __shared__ int sb[256];
    __shared__ int s[256];
    int t = threadIdx.x;
    int bv = (t < NBLK) ? bsum[t] : 0;
    sb[t] = bv;
    __syncthreads();
    #pragma unroll
    for (int off = 1; off < 256; off <<= 1) {
        int x = (t >= off) ? sb[t - off] : 0;
        __syncthreads();
        sb[t] += x;
        __syncthreads();
    }
    int bprefix = sb[blockIdx.x] - bsum[blockIdx.x];

    int i = blockIdx.x * 256 + t;
    int v = count[i];
    s[t] = v;
    __syncthreads();
    #pragma unroll
    for (int off = 1; off < 256; off <<= 1) {
        int x = (t >= off) ? s[t - off] : 0;
        __syncthreads();
        s[t] += x;
        __syncthreads();
    }
    int b = s[t] - v + bprefix;
    base[i] = b;
    if ((i & 127) == 0) bcur[i >> 7] = b;
}

// -------- in-place counting sort of each bucket segment (per-node order) ----
__global__ __launch_bounds__(512)
void k_sortb(const int* __restrict__ base, uint2* __restrict__ rec,
             int* __restrict__ flag) {
    __shared__ uint2 buf[SORT_CAP];
    __shared__ int lc[128];
    const int b = blockIdx.x;
    const int t = threadIdx.x;
    const int seg0 = base[b * 128];
    const int segend = base[b * 128 + 128];
    const int cnt_b = segend - seg0;
    if (cnt_b > SORT_CAP) {
        if (t == 0) flag[b] = 1;    // k_agg falls back to segment scan
        return;
    }
    if (t < 128) lc[t] = base[b * 128 + t] - seg0;
    __syncthreads();
    for (int k = t; k < cnt_b; k += 512) {
        uint2 rr = rec[seg0 + k];
        int nl = (rr.x >> 20) & 127;
        int p = atomicAdd(&lc[nl], 1);
        buf[p] = rr;
    }
    __syncthreads();
    for (int k = t; k < cnt_b; k += 512)
        rec[seg0 + k] = buf[k];
}

// ------ aggregate: one wave per dst node, 16 lanes x uint2 per record -------
__global__ __launch_bounds__(256)
void k_agg(const int* __restrict__ base, const int* __restrict__ cnt,
           const uint2* __restrict__ rec, const u16* __restrict__ xr,
           const int* __restrict__ flag, float* __restrict__ out) {
    int n = (blockIdx.x * 256 + threadIdx.x) >> 6;
    int L = threadIdx.x & 63;
    if (n >= NN) return;
    const int g = L >> 4;        // record group 0..3
    const int c = L & 15;        // cols 4c..4c+3
    float a0 = 0.f, a1 = 0.f, a2 = 0.f, a3 = 0.f;

    if (__builtin_expect(flag[n >> 7], 0)) {
        // slow path: unsorted bucket — scan whole segment, filter by dst_local
        int seg0 = base[n & ~127];
        int segend = base[(n & ~127) + 128];
        int my = n & 127;
        for (int k = seg0 + g; k < segend; k += 4) {
            uint2 rr = rec[k];
            if (((rr.x >> 20) & 127) == (u32)my) {
                size_t rw = ((size_t)((rr.x >> 16) & 0xFu) * NN + (rr.x & 0xFFFFu)) * DD;
                uint2 u = *reinterpret_cast<const uint2*>(&xr[rw + 4 * c]);
                float nm = __uint_as_float(rr.y);
                a0 = fmaf(__uint_as_float((u.x & 0xFFFFu) << 16), nm, a0);
                a1 = fmaf(__uint_as_float(u.x & 0xFFFF0000u), nm, a1);
                a2 = fmaf(__uint_as_float((u.y & 0xFFFFu) << 16), nm, a2);
                a3 = fmaf(__uint_as_float(u.y & 0xFFFF0000u), nm, a3);
            }
        }
    } else {
        int st = base[n];
        int cn = cnt[n];
        int k = 0;
        for (; k + 8 <= cn; k += 8) {
            uint2 r0 = rec[st + k + g];
            uint2 r1 = rec[st + k + 4 + g];
            size_t w0 = ((size_t)((r0.x >> 16) & 0xFu) * NN + (r0.x & 0xFFFFu)) * DD;
            size_t w1 = ((size_t)((r1.x >> 16) & 0xFu) * NN + (r1.x & 0xFFFFu)) * DD;
            uint2 u0 = *reinterpret_cast<const uint2*>(&xr[w0 + 4 * c]);
            uint2 u1 = *reinterpret_cast<const uint2*>(&xr[w1 + 4 * c]);
            float n0 = __uint_as_float(r0.y), n1 = __uint_as_float(r1.y);
            a0 = fmaf(__uint_as_float((u0.x & 0xFFFFu) << 16), n0, a0);
            a1 = fmaf(__uint_as_float(u0.x & 0xFFFF0000u), n0, a1);
            a2 = fmaf(__uint_as_float((u0.y & 0xFFFFu) << 16), n0, a2);
            a3 = fmaf(__uint_as_float(u0.y & 0xFFFF0000u), n0, a3);
            a0 = fmaf(__uint_as_float((u1.x & 0xFFFFu) << 16), n1, a0);
            a1 = fmaf(__uint_as_float(u1.x & 0xFFFF0000u), n1, a1);
            a2 = fmaf(__uint_as_float((u1.y & 0xFFFFu) << 16), n1, a2);
            a3 = fmaf(__uint_as_float(u1.y & 0xFFFF0000u), n1, a3);
        }
        for (int kk = k + g; kk < cn; kk += 4) {
            uint2 rr = rec[st + kk];
            size_t rw = ((size_t)((rr.x >> 16) & 0xFu) * NN + (rr.x & 0xFFFFu)) * DD;
            uint2 u = *reinterpret_cast<const uint2*>(&xr[rw + 4 * c]);
            float nm = __uint_as_float(rr.y);
            a0 = fmaf(__uint_as_float((u.x & 0xFFFFu) << 16), nm, a0);
            a1 = fmaf(__uint_as_float(u.x & 0xFFFF0000u), nm, a1);
            a2 = fmaf(__uint_as_float((u.y & 0xFFFFu) << 16), nm, a2);
            a3 = fmaf(__uint_as_float(u.y & 0xFFFF0000u), nm, a3);
        }
    }
    a0 += __shfl_xor(a0, 16); a1 += __shfl_xor(a1, 16);
    a2 += __shfl_xor(a2, 16); a3 += __shfl_xor(a3, 16);
    a0 += __shfl_xor(a0, 32); a1 += __shfl_xor(a1, 32);
    a2 += __shfl_xor(a2, 32); a3 += __shfl_xor(a3, 32);
    if (g == 0) {
        size_t o = (size_t)n * DD + 4 * c;
        float4 v = *reinterpret_cast<const float4*>(&out[o]);
        v.x = fmaxf(v.x + a0, 0.f);
        v.y = fmaxf(v.y + a1, 0.f);
        v.z = fmaxf(v.z + a2, 0.f);
        v.w = fmaxf(v.w + a3, 0.f);
        *reinterpret_cast<float4*>(&out[o]) = v;
    }
}

// ---------------- fallbacks ----------------
__global__ __launch_bounds__(256)
void k_edges(const int* __restrict__ src, const int* __restrict__ dst,
             const int* __restrict__ etype, const float* __restrict__ norm,
             const u16* __restrict__ xr, float* __restrict__ out) {
    int gtid = blockIdx.x * 256 + threadIdx.x;
    int e = gtid >> 4;
    int l = gtid & 15;
    if (e >= EE) return;
    int s = src[e];
    int d = dst[e];
    int rt = etype[e];
    float nm = norm[e];
    size_t row = ((size_t)rt * NN + s) * DD;
    uint2 u = *reinterpret_cast<const uint2*>(&xr[row + l * 4]);
    float f0 = __uint_as_float((u.x & 0xFFFFu) << 16);
    float f1 = __uint_as_float(u.x & 0xFFFF0000u);
    float f2 = __uint_as_float((u.y & 0xFFFFu) << 16);
    float f3 = __uint_as_float(u.y & 0xFFFF0000u);
    float* op = out + (size_t)d * DD + l * 4;
    atomicAdd(op + 0, f0 * nm);
    atomicAdd(op + 1, f1 * nm);
    atomicAdd(op + 2, f2 * nm);
    atomicAdd(op + 3, f3 * nm);
}

__global__ void k_makeW(const float* __restrict__ weight,
                        const float* __restrict__ w_comp,
                        float* __restrict__ W) {
    int f = blockIdx.x * 256 + threadIdx.x;
    if (f >= RR * 4096) return;
    int r = f >> 12;
    int io = f & 4095;
    float v = 0.f;
    #pragma unroll
    for (int b = 0; b < BB; ++b) v += w_comp[r * BB + b] * weight[b * 4096 + io];
    W[f] = v;
}

__global__ __launch_bounds__(256)
void k_edges_direct(const int* __restrict__ src, const int* __restrict__ dst,
                    const int* __restrict__ etype, const float* __restrict__ norm,
                    const float* __restrict__ feat, const float* __restrict__ W,
                    float* __restrict__ out) {
    int gtid = blockIdx.x * 256 + threadIdx.x;
    int e = gtid >> 6;
    int lane = gtid & 63;
    if (e >= EE) return;
    int s = src[e];
    int d = dst[e];
    int rt = etype[e];
    float nm = norm[e];
    const float* fr = feat + (size_t)s * DD;
    const float* Wr = W + (size_t)rt * 4096;
    float acc = 0.f;
    #pragma unroll
    for (int i = 0; i < DD; ++i) acc = fmaf(fr[i], Wr[i * DD + lane], acc);
    atomicAdd(&out[(size_t)d * DD + lane], acc * nm);
}

__global__ __launch_bounds__(256)
void k_relu(float* __restrict__ out) {
    int i = blockIdx.x * 256 + threadIdx.x;
    float4* p = reinterpret_cast<float4*>(out);
    float4 v = p[i];
    v.x = fmaxf(v.x, 0.f);
    v.y = fmaxf(v.y, 0.f);
    v.z = fmaxf(v.z, 0.f);
    v.w = fmaxf(v.w, 0.f);
    p[i] = v;
}

extern "C" void kernel_launch(void* const* d_in, const int* in_sizes, int n_in,
                              void* d_out, int out_size, void* d_ws, size_t ws_size,
                              hipStream_t stream) {
    const float* feat   = (const float*)d_in[0];
    const int*   src    = (const int*)d_in[1];
    const int*   dst    = (const int*)d_in[2];
    const int*   etype  = (const int*)d_in[3];
    const float* norm   = (const float*)d_in[4];
    const float* weight = (const float*)d_in[5];
    const float* w_comp = (const float*)d_in[6];
    const float* self_w = (const float*)d_in[7];
    float* out = (float*)d_out;

    const size_t sz_xr    = (size_t)RR * NN * DD * sizeof(u16);   // 64,000,000
    const size_t off_cnt  = sz_xr;                                 // NPAD ints
    const size_t off_flag = off_cnt + (size_t)NPAD * 4;            // 392 ints
    const size_t off_bsum = off_flag + 1568;                       // 256 ints
    const size_t off_base = off_bsum + 1024;                       // NPAD ints
    const size_t off_bcur = off_base + (size_t)NPAD * 4;           // 392 ints
    const size_t off_rec  = off_bcur + 1568;                       // EE uint2
    const size_t need_full = off_rec + (size_t)EE * 8;             // ~70.8 MB

    dim3 blk(256);
    char* ws = (char*)d_ws;

    if (ws_size >= need_full) {
        u16*  xr    = (u16*)ws;
        int*  cnt   = (int*)(ws + off_cnt);
        int*  flag  = (int*)(ws + off_flag);
        int*  bsum  = (int*)(ws + off_bsum);
        int*  basep = (int*)(ws + off_base);
        int*  bcur  = (int*)(ws + off_bcur);
        uint2* rec  = (uint2*)(ws + off_rec);

        hipMemsetAsync(cnt, 0, (size_t)NPAD * 4 + 1568, stream);  // cnt + flag
        k_hist<<<dim3((EE + 255) / 256), blk, 0, stream>>>(dst, cnt);
        k_blocksum<<<dim3(NBLK), blk, 0, stream>>>(cnt, bsum);
        k_offsets2<<<dim3(NBLK), blk, 0, stream>>>(cnt, bsum, basep, bcur);
        k_big<<<dim3(TBLK + BBLK), blk, 0, stream>>>(feat, weight, w_comp, self_w,
                                                     src, dst, etype, norm,
                                                     bcur, rec, xr, out, TBLK, 0);
        k_sortb<<<dim3(391), dim3(512), 0, stream>>>(basep, rec, flag);
        k_agg<<<dim3((NN * 64 + 255) / 256), blk, 0, stream>>>(basep, cnt, rec, xr,
                                                               flag, out);
    } else if (ws_size >= sz_xr) {
        u16* xr = (u16*)d_ws;
        k_big<<<dim3(TBLK), blk, 0, stream>>>(feat, weight, w_comp, self_w,
                                              src, dst, etype, norm,
                                              (int*)d_ws, (uint2*)d_ws, xr, out,
                                              TBLK, 0);
        k_edges<<<dim3(EE * 16 / 256), blk, 0, stream>>>(src, dst, etype, norm, xr, out);
        k_relu<<<dim3(NN * DD / 4 / 256), blk, 0, stream>>>(out);
    } else {
        k_big<<<dim3(391), blk, 0, stream>>>(feat, weight, w_comp, self_w,
                                             src, dst, etype, norm,
                                             (int*)d_ws, (uint2*)d_ws, (u16*)d_ws, out,
                                             391, 3910);
        float* W = (float*)d_ws;
        k_makeW<<<dim3(160), blk, 0, stream>>>(weight, w_comp, W);
        k_edges_direct<<<dim3(EE * 64 / 256), blk, 0, stream>>>(src, dst, etype, norm,
                                                                feat, W, out);
        k_relu<<<dim3(NN * DD / 4 / 256), blk, 0, stream>>>(out);
    }
}

// Round 7
// 178.311 us; speedup vs baseline: 3.1039x; 1.2421x over previous
//
#include <hip/hip_runtime.h>
#include <hip/hip_bf16.h>
#include <stdint.h>

#define NN 50000
#define EE 800000
#define DD 64
#define RR 10
#define BB 4
#define NPAD 50176
#define NBKT 391            // buckets of 128 nodes
#define TBLK 4301           // 391 * 11 transform blocks in k_big
#define BBLK 196            // bin blocks in k_big (4096 edges each)
#define SORT_CAP 7168       // max records per bucket for in-LDS sort
#define FCAP 4096           // fixed-capacity bucket stride (opportunistic path)

using u16 = unsigned short;
using u32 = unsigned int;

typedef short v8s __attribute__((ext_vector_type(8)));
typedef float v4f __attribute__((ext_vector_type(4)));

__device__ __forceinline__ u32 f2bf_rn(float x) {
    u32 u = __float_as_uint(x);
    return (u + 0x7FFFu + ((u >> 16) & 1u)) >> 16;
}
__device__ __forceinline__ u32 pack2bf(float a, float b) {
    return f2bf_rn(a) | (f2bf_rn(b) << 16);
}

// ============ mega-kernel: transform blocks + bucket-bin blocks ============
// rec word0 = src(16b) | etype(4b @16) | dst_local(7b @20)
// cap==0: hist mode (bcur preset to exact bucket bases, no overflow possible)
// cap>0 : fixed mode (bcur preset to b*cap; guard + flag|=2 on overflow)
__global__ __launch_bounds__(256, 2)
void k_big(const float* __restrict__ feat,
           const float* __restrict__ weight,
           const float* __restrict__ w_comp,
           const float* __restrict__ self_w,
           const int* __restrict__ src, const int* __restrict__ dst,
           const int* __restrict__ etype, const float* __restrict__ norm,
           int* __restrict__ bcur, int* __restrict__ flag,
           uint2* __restrict__ rec,
           u16* __restrict__ xr, float* __restrict__ out,
           int tcount, int tb_off, int cap) {
    __shared__ __align__(16) char smem[34816];
    const int t = threadIdx.x;

    if ((int)blockIdx.x >= tcount) {
        // ---------------- bucket binning, batched reservations --------------
        int* lh  = (int*)smem;
        int* gb  = lh + 392;
        int* lcc = gb + 392;
        const int ebase = ((int)blockIdx.x - tcount) * 4096;
        for (int b = t; b < 392; b += 256) { lh[b] = 0; lcc[b] = 0; }
        __syncthreads();
        #pragma unroll 4
        for (int j = 0; j < 16; ++j) {
            int e = ebase + t + 256 * j;
            if (e < EE) atomicAdd(&lh[dst[e] >> 7], 1);
        }
        __syncthreads();
        for (int b = t; b < 392; b += 256) {
            int c = lh[b];
            gb[b] = c ? atomicAdd(&bcur[b], c) : 0;
        }
        __syncthreads();
        #pragma unroll 4
        for (int j = 0; j < 16; ++j) {
            int e = ebase + t + 256 * j;
            if (e < EE) {
                int d = dst[e];
                int b = d >> 7;
                int p = atomicAdd(&lcc[b], 1);
                int idx = gb[b] + p;
                u32 w0 = (u32)src[e] | ((u32)etype[e] << 16) | ((u32)(d & 127) << 20);
                if (cap == 0 || idx < (b + 1) * cap)
                    rec[idx] = make_uint2(w0, __float_as_uint(norm[e]));
                else
                    atomicOr(&flag[b], 2);   // overflow: k_agg edge-rescan path
            }
        }
        return;
    }

    // ---------------- transform ----------------
    u16*   sWt = (u16*)smem;                  // Wt[n][k], stride 72 u16
    u16*   sFb = (u16*)(smem + 9216);         // feat bf16 [128][72]
    float* sD  = (float*)smem;                // epilogue transpose [128][68]

    const int tb = (int)blockIdx.x + tb_off;
    const int r = tb / 391;
    const int nbase = (tb % 391) * 128;

    if (r < RR) {
        const float c0 = w_comp[r * BB + 0];
        const float c1 = w_comp[r * BB + 1];
        const float c2 = w_comp[r * BB + 2];
        const float c3 = w_comp[r * BB + 3];
        #pragma unroll
        for (int qq = 0; qq < 16; ++qq) {
            int idx = t + 256 * qq;
            int n = idx & 63, k = idx >> 6;
            float v = c0 * weight[k * 64 + n] + c1 * weight[4096 + k * 64 + n] +
                      c2 * weight[8192 + k * 64 + n] + c3 * weight[12288 + k * 64 + n];
            sWt[n * 72 + k] = (u16)f2bf_rn(v);
        }
    } else {
        #pragma unroll
        for (int qq = 0; qq < 16; ++qq) {
            int idx = t + 256 * qq;
            int n = idx & 63, k = idx >> 6;
            sWt[n * 72 + k] = (u16)f2bf_rn(self_w[k * 64 + n]);
        }
    }

    #pragma unroll
    for (int qq = 0; qq < 8; ++qq) {
        int f4 = qq * 256 + t;
        int nl = f4 >> 4;
        int ic = (f4 & 15) << 2;
        int n = nbase + nl;
        float4 v = make_float4(0.f, 0.f, 0.f, 0.f);
        if (n < NN) v = reinterpret_cast<const float4*>(feat)[(size_t)n * 16 + (f4 & 15)];
        *reinterpret_cast<uint2*>(&sFb[nl * 72 + ic]) =
            make_uint2(pack2bf(v.x, v.y), pack2bf(v.z, v.w));
    }
    __syncthreads();

    const int wv = t >> 6;
    const int L = t & 63;
    const int q = L >> 4;
    const int c = L & 15;

    v8s bf[4][2];
    #pragma unroll
    for (int nt = 0; nt < 4; ++nt)
        #pragma unroll
        for (int kh = 0; kh < 2; ++kh)
            bf[nt][kh] = *reinterpret_cast<const v8s*>(&sWt[(nt * 16 + c) * 72 + kh * 32 + q * 8]);

    v8s af[2][2];
    #pragma unroll
    for (int mt = 0; mt < 2; ++mt) {
        int row = wv * 32 + mt * 16 + c;
        #pragma unroll
        for (int kh = 0; kh < 2; ++kh)
            af[mt][kh] = *reinterpret_cast<const v8s*>(&sFb[row * 72 + kh * 32 + q * 8]);
    }
    __syncthreads();

    v4f acc[2][4];
    #pragma unroll
    for (int mt = 0; mt < 2; ++mt)
        #pragma unroll
        for (int nt = 0; nt < 4; ++nt) {
            acc[mt][nt] = (v4f)(0.f);
            #pragma unroll
            for (int kh = 0; kh < 2; ++kh)
                acc[mt][nt] = __builtin_amdgcn_mfma_f32_16x16x32_bf16(
                    af[mt][kh], bf[nt][kh], acc[mt][nt], 0, 0, 0);
        }

    #pragma unroll
    for (int mt = 0; mt < 2; ++mt) {
        int mrow = wv * 32 + mt * 16 + q * 4;
        #pragma unroll
        for (int nt = 0; nt < 4; ++nt)
            #pragma unroll
            for (int rg = 0; rg < 4; ++rg)
                sD[(mrow + rg) * 68 + nt * 16 + c] = acc[mt][nt][rg];
    }
    __syncthreads();

    const int row = t >> 1;
    const int cb = (t & 1) * 32;
    const int g = nbase + row;
    if (g < NN) {
        const float* sp = &sD[row * 68 + cb];
        if (r < RR) {
            u16* dp = xr + ((size_t)r * NN + g) * DD + cb;
            #pragma unroll
            for (int j = 0; j < 4; ++j) {
                float4 f0 = *reinterpret_cast<const float4*>(sp + j * 8);
                float4 f1 = *reinterpret_cast<const float4*>(sp + j * 8 + 4);
                uint4 o;
                o.x = pack2bf(f0.x, f0.y);
                o.y = pack2bf(f0.z, f0.w);
                o.z = pack2bf(f1.x, f1.y);
                o.w = pack2bf(f1.z, f1.w);
                *reinterpret_cast<uint4*>(dp + j * 8) = o;
            }
        } else {
            float* dp = out + (size_t)g * DD + cb;
            #pragma unroll
            for (int j = 0; j < 8; ++j)
                *reinterpret_cast<float4*>(dp + j * 4) =
                    *reinterpret_cast<const float4*>(sp + j * 4);
        }
    }
}

// ---------------- fixed-mode init: bucket cursors + flags ----------------
__global__ __launch_bounds__(256)
void k_init(int* __restrict__ bcur, int* __restrict__ flag) {
    int t = blockIdx.x * 256 + threadIdx.x;
    if (t < 392) { bcur[t] = t * FCAP; flag[t] = 0; }
}

// ---------------- bucket histogram (hist mode) ----------------
__global__ __launch_bounds__(256)
void k_bhist(const int* __restrict__ dst, int* __restrict__ bktcnt) {
    __shared__ int lh[NBKT];
    const int t = threadIdx.x;
    for (int b = t; b < NBKT; b += 256) lh[b] = 0;
    __syncthreads();
    const int ebase = blockIdx.x * 8192;
    #pragma unroll
    for (int j = 0; j < 32; ++j) {
        int e = ebase + t + 256 * j;
        if (e < EE) atomicAdd(&lh[dst[e] >> 7], 1);
    }
    __syncthreads();
    for (int b = t; b < NBKT; b += 256) {
        int v = lh[b];
        if (v) atomicAdd(&bktcnt[b], v);
    }
}

// ---------------- bucket scan (hist mode): bases + cursors + flag=0 --------
__global__ __launch_bounds__(512)
void k_bscan(const int* __restrict__ bktcnt, int* __restrict__ bktbase,
             int* __restrict__ bcur, int* __restrict__ flag) {
    __shared__ int s[512];
    int t = threadIdx.x;
    int v = (t < NBKT) ? bktcnt[t] : 0;
    s[t] = v;
    __syncthreads();
    #pragma unroll
    for (int off = 1; off < 512; off <<= 1) {
        int x = (t >= off) ? s[t - off] : 0;
        __syncthreads();
        s[t] += x;
        __syncthreads();
    }
    if (t < 392) {
        int b = s[t] - v;
        bktbase[t] = b;
        bcur[t] = b;
        flag[t] = 0;
    }
}

// ------ sort bucket segment in place + emit per-node base/cnt ------
__global__ __launch_bounds__(512)
void k_sortb2(const int* __restrict__ bcurF, const int* __restrict__ bktbase,
              int* __restrict__ flag, uint2* __restrict__ rec,
              int* __restrict__ base, int* __restrict__ cnt, int cap) {
    __shared__ uint2 buf[SORT_CAP];
    __shared__ int h[128];
    __shared__ int sc[128];
    __shared__ int lc[128];
    const int b = blockIdx.x;
    const int t = threadIdx.x;
    const int seg0 = cap ? b * cap : bktbase[b];
    const int cnt_b = bcurF[b] - seg0;
    if (flag[b] & 2) return;                 // overflow during binning
    if (cnt_b > SORT_CAP) {
        if (t == 0) flag[b] = 1;             // rec-scan fallback in k_agg
        return;
    }
    if (t < 128) h[t] = 0;
    __syncthreads();
    // histogram of dst_local
    for (int k = t; k < cnt_b; k += 512) {
        uint2 rr = rec[seg0 + k];
        buf[k] = rr;
        atomicAdd(&h[(rr.x >> 20) & 127], 1);
    }
    __syncthreads();
    // exclusive scan of 128 counts
    if (t < 128) sc[t] = h[t];
    __syncthreads();
    #pragma unroll
    for (int off = 1; off < 128; off <<= 1) {
        int x = 0;
        if (t < 128 && t >= off) x = sc[t - off];
        __syncthreads();
        if (t < 128) sc[t] += x;
        __syncthreads();
    }
    if (t < 128) {
        int ex = sc[t] - h[t];
        lc[t] = ex;
        base[b * 128 + t] = seg0 + ex;
        cnt[b * 128 + t] = h[t];
    }
    __syncthreads();
    // scatter into sorted order (LDS cursor per node), then coalesced writeback
    for (int k = t; k < cnt_b; k += 512) {
        uint2 rr = buf[k];
        int p = atomicAdd(&lc[(rr.x >> 20) & 127], 1);
        rec[seg0 + p] = rr;
    }
}

// ------ aggregate: one wave per dst node, 16 records in flight -------
__global__ __launch_bounds__(256)
void k_agg(const int* __restrict__ base, const int* __restrict__ cnt,
           const uint2* __restrict__ rec, const u16* __restrict__ xr,
           const int* __restrict__ flag, const int* __restrict__ bktbase,
           const int* __restrict__ bcurF,
           const int* __restrict__ src, const int* __restrict__ dst,
           const int* __restrict__ etype, const float* __restrict__ norm,
           int cap, float* __restrict__ out) {
    int n = (blockIdx.x * 256 + threadIdx.x) >> 6;
    int L = threadIdx.x & 63;
    if (n >= NN) return;
    const int g = L >> 4;        // record group 0..3
    const int c = L & 15;        // cols 4c..4c+3
    float a0 = 0.f, a1 = 0.f, a2 = 0.f, a3 = 0.f;
    const int fb = flag[n >> 7];

    if (__builtin_expect(fb == 0, 1)) {
        int st = base[n];
        int cn = cnt[n];
        int k = 0;
        for (; k + 16 <= cn; k += 16) {
            uint2 r0 = rec[st + k + g];
            uint2 r1 = rec[st + k + 4 + g];
            uint2 r2 = rec[st + k + 8 + g];
            uint2 r3 = rec[st + k + 12 + g];
            size_t w0 = ((size_t)((r0.x >> 16) & 0xFu) * NN + (r0.x & 0xFFFFu)) * DD;
            size_t w1 = ((size_t)((r1.x >> 16) & 0xFu) * NN + (r1.x & 0xFFFFu)) * DD;
            size_t w2 = ((size_t)((r2.x >> 16) & 0xFu) * NN + (r2.x & 0xFFFFu)) * DD;
            size_t w3 = ((size_t)((r3.x >> 16) & 0xFu) * NN + (r3.x & 0xFFFFu)) * DD;
            uint2 u0 = *reinterpret_cast<const uint2*>(&xr[w0 + 4 * c]);
            uint2 u1 = *reinterpret_cast<const uint2*>(&xr[w1 + 4 * c]);
            uint2 u2 = *reinterpret_cast<const uint2*>(&xr[w2 + 4 * c]);
            uint2 u3 = *reinterpret_cast<const uint2*>(&xr[w3 + 4 * c]);
            float n0 = __uint_as_float(r0.y), n1 = __uint_as_float(r1.y);
            float n2 = __uint_as_float(r2.y), n3 = __uint_as_float(r3.y);
            a0 = fmaf(__uint_as_float((u0.x & 0xFFFFu) << 16), n0, a0);
            a1 = fmaf(__uint_as_float(u0.x & 0xFFFF0000u), n0, a1);
            a2 = fmaf(__uint_as_float((u0.y & 0xFFFFu) << 16), n0, a2);
            a3 = fmaf(__uint_as_float(u0.y & 0xFFFF0000u), n0, a3);
            a0 = fmaf(__uint_as_float((u1.x & 0xFFFFu) << 16), n1, a0);
            a1 = fmaf(__uint_as_float(u1.x & 0xFFFF0000u), n1, a1);
            a2 = fmaf(__uint_as_float((u1.y & 0xFFFFu) << 16), n1, a2);
            a3 = fmaf(__uint_as_float(u1.y & 0xFFFF0000u), n1, a3);
            a0 = fmaf(__uint_as_float((u2.x & 0xFFFFu) << 16), n2, a0);
            a1 = fmaf(__uint_as_float(u2.x & 0xFFFF0000u), n2, a1);
            a2 = fmaf(__uint_as_float((u2.y & 0xFFFFu) << 16), n2, a2);
            a3 = fmaf(__uint_as_float(u2.y & 0xFFFF0000u), n2, a3);
            a0 = fmaf(__uint_as_float((u3.x & 0xFFFFu) << 16), n3, a0);
            a1 = fmaf(__uint_as_float(u3.x & 0xFFFF0000u), n3, a1);
            a2 = fmaf(__uint_as_float((u3.y & 0xFFFFu) << 16), n3, a2);
            a3 = fmaf(__uint_as_float(u3.y & 0xFFFF0000u), n3, a3);
        }
        for (int kk = k + g; kk < cn; kk += 4) {
            uint2 rr = rec[st + kk];
            size_t rw = ((size_t)((rr.x >> 16) & 0xFu) * NN + (rr.x & 0xFFFFu)) * DD;
            uint2 u = *reinterpret_cast<const uint2*>(&xr[rw + 4 * c]);
            float nm = __uint_as_float(rr.y);
            a0 = fmaf(__uint_as_float((u.x & 0xFFFFu) << 16), nm, a0);
            a1 = fmaf(__uint_as_float(u.x & 0xFFFF0000u), nm, a1);
            a2 = fmaf(__uint_as_float((u.y & 0xFFFFu) << 16), nm, a2);
            a3 = fmaf(__uint_as_float(u.y & 0xFFFF0000u), nm, a3);
        }
    } else if (fb & 2) {
        // binning overflow (adversarial input only): rescan the edge list
        for (int e = g; e < EE; e += 4) {
            if (dst[e] == n) {
                size_t rw = ((size_t)etype[e] * NN + src[e]) * DD;
                uint2 u = *reinterpret_cast<const uint2*>(&xr[rw + 4 * c]);
                float nm = norm[e];
                a0 = fmaf(__uint_as_float((u.x & 0xFFFFu) << 16), nm, a0);
                a1 = fmaf(__uint_as_float(u.x & 0xFFFF0000u), nm, a1);
                a2 = fmaf(__uint_as_float((u.y & 0xFFFFu) << 16), nm, a2);
                a3 = fmaf(__uint_as_float(u.y & 0xFFFF0000u), nm, a3);
            }
        }
    } else {
        // sort-capacity overflow: scan whole (unsorted) bucket segment
        int b = n >> 7;
        int seg0 = cap ? b * cap : bktbase[b];
        int segend = bcurF[b];
        int my = n & 127;
        for (int k = seg0 + g; k < segend; k += 4) {
            uint2 rr = rec[k];
            if (((rr.x >> 20) & 127) == (u32)my) {
                size_t rw = ((size_t)((rr.x >> 16) & 0xFu) * NN + (rr.x & 0xFFFFu)) * DD;
                uint2 u = *reinterpret_cast<const uint2*>(&xr[rw + 4 * c]);
                float nm = __uint_as_float(rr.y);
                a0 = fmaf(__uint_as_float((u.x & 0xFFFFu) << 16), nm, a0);
                a1 = fmaf(__uint_as_float(u.x & 0xFFFF0000u), nm, a1);
                a2 = fmaf(__uint_as_float((u.y & 0xFFFFu) << 16), nm, a2);
                a3 = fmaf(__uint_as_float(u.y & 0xFFFF0000u), nm, a3);
            }
        }
    }
    a0 += __shfl_xor(a0, 16); a1 += __shfl_xor(a1, 16);
    a2 += __shfl_xor(a2, 16); a3 += __shfl_xor(a3, 16);
    a0 += __shfl_xor(a0, 32); a1 += __shfl_xor(a1, 32);
    a2 += __shfl_xor(a2, 32); a3 += __shfl_xor(a3, 32);
    if (g == 0) {
        size_t o = (size_t)n * DD + 4 * c;
        float4 v = *reinterpret_cast<const float4*>(&out[o]);
        v.x = fmaxf(v.x + a0, 0.f);
        v.y = fmaxf(v.y + a1, 0.f);
        v.z = fmaxf(v.z + a2, 0.f);
        v.w = fmaxf(v.w + a3, 0.f);
        *reinterpret_cast<float4*>(&out[o]) = v;
    }
}

// ---------------- fallbacks ----------------
__global__ __launch_bounds__(256)
void k_edges(const int* __restrict__ src, const int* __restrict__ dst,
             const int* __restrict__ etype, const float* __restrict__ norm,
             const u16* __restrict__ xr, float* __restrict__ out) {
    int gtid = blockIdx.x * 256 + threadIdx.x;
    int e = gtid >> 4;
    int l = gtid & 15;
    if (e >= EE) return;
    int s = src[e];
    int d = dst[e];
    int rt = etype[e];
    float nm = norm[e];
    size_t row = ((size_t)rt * NN + s) * DD;
    uint2 u = *reinterpret_cast<const uint2*>(&xr[row + l * 4]);
    float f0 = __uint_as_float((u.x & 0xFFFFu) << 16);
    float f1 = __uint_as_float(u.x & 0xFFFF0000u);
    float f2 = __uint_as_float((u.y & 0xFFFFu) << 16);
    float f3 = __uint_as_float(u.y & 0xFFFF0000u);
    float* op = out + (size_t)d * DD + l * 4;
    atomicAdd(op + 0, f0 * nm);
    atomicAdd(op + 1, f1 * nm);
    atomicAdd(op + 2, f2 * nm);
    atomicAdd(op + 3, f3 * nm);
}

__global__ void k_makeW(const float* __restrict__ weight,
                        const float* __restrict__ w_comp,
                        float* __restrict__ W) {
    int f = blockIdx.x * 256 + threadIdx.x;
    if (f >= RR * 4096) return;
    int r = f >> 12;
    int io = f & 4095;
    float v = 0.f;
    #pragma unroll
    for (int b = 0; b < BB; ++b) v += w_comp[r * BB + b] * weight[b * 4096 + io];
    W[f] = v;
}

__global__ __launch_bounds__(256)
void k_edges_direct(const int* __restrict__ src, const int* __restrict__ dst,
                    const int* __restrict__ etype, const float* __restrict__ norm,
                    const float* __restrict__ feat, const float* __restrict__ W,
                    float* __restrict__ out) {
    int gtid = blockIdx.x * 256 + threadIdx.x;
    int e = gtid >> 6;
    int lane = gtid & 63;
    if (e >= EE) return;
    int s = src[e];
    int d = dst[e];
    int rt = etype[e];
    float nm = norm[e];
    const float* fr = feat + (size_t)s * DD;
    const float* Wr = W + (size_t)rt * 4096;
    float acc = 0.f;
    #pragma unroll
    for (int i = 0; i < DD; ++i) acc = fmaf(fr[i], Wr[i * DD + lane], acc);
    atomicAdd(&out[(size_t)d * DD + lane], acc * nm);
}

__global__ __launch_bounds__(256)
void k_relu(float* __restrict__ out) {
    int i = blockIdx.x * 256 + threadIdx.x;
    float4* p = reinterpret_cast<float4*>(out);
    float4 v = p[i];
    v.x = fmaxf(v.x, 0.f);
    v.y = fmaxf(v.y, 0.f);
    v.z = fmaxf(v.z, 0.f);
    v.w = fmaxf(v.w, 0.f);
    p[i] = v;
}

extern "C" void kernel_launch(void* const* d_in, const int* in_sizes, int n_in,
                              void* d_out, int out_size, void* d_ws, size_t ws_size,
                              hipStream_t stream) {
    const float* feat   = (const float*)d_in[0];
    const int*   src    = (const int*)d_in[1];
    const int*   dst    = (const int*)d_in[2];
    const int*   etype  = (const int*)d_in[3];
    const float* norm   = (const float*)d_in[4];
    const float* weight = (const float*)d_in[5];
    const float* w_comp = (const float*)d_in[6];
    const float* self_w = (const float*)d_in[7];
    float* out = (float*)d_out;

    const size_t sz_xr     = (size_t)RR * NN * DD * sizeof(u16);  // 64,000,000
    const size_t off_bkc   = sz_xr;                 // bktcnt 392 ints -> 1600
    const size_t off_bkb   = off_bkc + 1600;        // bktbase 392 ints -> 1600
    const size_t off_bcur  = off_bkb + 1600;        // bcur 392 ints -> 1600
    const size_t off_flag  = off_bcur + 1600;       // flag 392 ints -> 1600
    const size_t off_base  = off_flag + 1600;       // NPAD ints
    const size_t off_cnt   = off_base + (size_t)NPAD * 4;
    const size_t off_rec   = off_cnt + (size_t)NPAD * 4;
    const size_t need_hist  = off_rec + (size_t)EE * 8;            // ~70.8 MB
    const size_t need_fixed = off_rec + (size_t)NBKT * FCAP * 8;   // ~77.2 MB

    dim3 blk(256);
    char* ws = (char*)d_ws;

    if (ws_size >= need_hist) {
        u16*  xr      = (u16*)ws;
        int*  bktcnt  = (int*)(ws + off_bkc);
        int*  bktbase = (int*)(ws + off_bkb);
        int*  bcur    = (int*)(ws + off_bcur);
        int*  flag    = (int*)(ws + off_flag);
        int*  basep   = (int*)(ws + off_base);
        int*  cntp    = (int*)(ws + off_cnt);
        uint2* rec    = (uint2*)(ws + off_rec);
        const int cap = (ws_size >= need_fixed) ? FCAP : 0;

        if (cap) {
            k_init<<<dim3(2), blk, 0, stream>>>(bcur, flag);
        } else {
            hipMemsetAsync(bktcnt, 0, 1600, stream);
            k_bhist<<<dim3(98), blk, 0, stream>>>(dst, bktcnt);
            k_bscan<<<dim3(1), dim3(512), 0, stream>>>(bktcnt, bktbase, bcur, flag);
        }
        k_big<<<dim3(TBLK + BBLK), blk, 0, stream>>>(feat, weight, w_comp, self_w,
                                                     src, dst, etype, norm,
                                                     bcur, flag, rec, xr, out,
                                                     TBLK, 0, cap);
        k_sortb2<<<dim3(NBKT), dim3(512), 0, stream>>>(bcur, bktbase, flag, rec,
                                                       basep, cntp, cap);
        k_agg<<<dim3((NN * 64 + 255) / 256), blk, 0, stream>>>(
            basep, cntp, rec, xr, flag, bktbase, bcur,
            src, dst, etype, norm, cap, out);
    } else if (ws_size >= sz_xr) {
        u16* xr = (u16*)d_ws;
        k_big<<<dim3(TBLK), blk, 0, stream>>>(feat, weight, w_comp, self_w,
                                              src, dst, etype, norm,
                                              (int*)d_ws, (int*)d_ws, (uint2*)d_ws,
                                              xr, out, TBLK, 0, 0);
        k_edges<<<dim3(EE * 16 / 256), blk, 0, stream>>>(src, dst, etype, norm, xr, out);
        k_relu<<<dim3(NN * DD / 4 / 256), blk, 0, stream>>>(out);
    } else {
        k_big<<<dim3(391), blk, 0, stream>>>(feat, weight, w_comp, self_w,
                                             src, dst, etype, norm,
                                             (int*)d_ws, (int*)d_ws, (uint2*)d_ws,
                                             (u16*)d_ws, out, 391, 3910, 0);
        float* W = (float*)d_ws;
        k_makeW<<<dim3(160), blk, 0, stream>>>(weight, w_comp, W);
        k_edges_direct<<<dim3(EE * 64 / 256), blk, 0, stream>>>(src, dst, etype, norm,
                                                                feat, W, out);
        k_relu<<<dim3(NN * DD / 4 / 256), blk, 0, stream>>>(out);
    }
}